// Round 1
// baseline (209.263 us; speedup 1.0000x reference)
//
#include <hip/hip_runtime.h>
#include <stdint.h>

#define BATCH 2
#define SEQ   2048
#define EMB   1024
#define NH    16
#define HD    64
#define MROWS (BATCH*SEQ)   // 4096

using bf16x8 = __attribute__((ext_vector_type(8))) short;
using f32x4  = __attribute__((ext_vector_type(4))) float;

__device__ __forceinline__ unsigned short f2bf(float f) {
  __bf16 b = (__bf16)f;                       // RNE fptrunc
  return __builtin_bit_cast(unsigned short, b);
}

__device__ __forceinline__ void async_load16(const void* g, void* l) {
  __builtin_amdgcn_global_load_lds(
      (__attribute__((address_space(1))) void*)g,
      (__attribute__((address_space(3))) void*)l,
      16, 0, 0);
}

// ---------------- f32 -> bf16 bulk convert ----------------
__global__ __launch_bounds__(256) void convert_kernel(
    const float* __restrict__ in, unsigned short* __restrict__ out, int n4) {
  int i = blockIdx.x * blockDim.x + threadIdx.x;
  if (i >= n4) return;
  const float4 v = reinterpret_cast<const float4*>(in)[i];
  ushort4 o;
  o.x = f2bf(v.x); o.y = f2bf(v.y); o.z = f2bf(v.z); o.w = f2bf(v.w);
  reinterpret_cast<ushort4*>(out)[i] = o;
}

// ---------------- weight transpose + convert: Wt[n][k] = W[k][n] ----------------
__global__ __launch_bounds__(256) void transw_kernel(
    const float* __restrict__ Wq, const float* __restrict__ Wk,
    const float* __restrict__ Wv, const float* __restrict__ Wo,
    unsigned short* __restrict__ WtAll) {
  const int z = blockIdx.z;
  const float* W = (z == 0) ? Wq : (z == 1) ? Wk : (z == 2) ? Wv : Wo;
  unsigned short* Wt = WtAll + (size_t)z * EMB * EMB;
  __shared__ unsigned short tile[64][65];
  const int tc = threadIdx.x & 15;
  const int tr = threadIdx.x >> 4;
  const int n0 = blockIdx.x * 64, k0 = blockIdx.y * 64;
#pragma unroll
  for (int rr = 0; rr < 4; ++rr) {
    const int row = rr * 16 + tr;  // k-local
    float4 v = *reinterpret_cast<const float4*>(W + (size_t)(k0 + row) * EMB + n0 + tc * 4);
    tile[tc * 4 + 0][row] = f2bf(v.x);
    tile[tc * 4 + 1][row] = f2bf(v.y);
    tile[tc * 4 + 2][row] = f2bf(v.z);
    tile[tc * 4 + 3][row] = f2bf(v.w);
  }
  __syncthreads();
#pragma unroll
  for (int rr = 0; rr < 4; ++rr) {
    const int row = rr * 16 + tr;  // n-local
    ushort4 o;
    o.x = tile[row][tc * 4 + 0];
    o.y = tile[row][tc * 4 + 1];
    o.z = tile[row][tc * 4 + 2];
    o.w = tile[row][tc * 4 + 3];
    *reinterpret_cast<ushort4*>(Wt + (size_t)(n0 + row) * EMB + k0 + tc * 4) = o;
  }
}

// ---------------- GEMM: C[m][n] = A[m][:] . Wt[n][:] + bias[n] ----------------
// m97 structure: 128x128 tile, BK=32, 4 waves (2x2 of 64x64), global_load_lds w=16.
#define BM 128
#define BN 128
#define BK 32

__global__ __launch_bounds__(256, 2) void gemm_kernel(
    const unsigned short* __restrict__ xb,
    const unsigned short* __restrict__ yb,
    const unsigned short* __restrict__ attnb,
    const unsigned short* __restrict__ WtAll,
    const float* __restrict__ bq, const float* __restrict__ bk,
    const float* __restrict__ bv, const float* __restrict__ bo,
    unsigned short* __restrict__ Qb, unsigned short* __restrict__ Kb,
    unsigned short* __restrict__ Vt, float* __restrict__ dout,
    int phase) {
  __shared__ __align__(16) unsigned short As[BM * BK];
  __shared__ __align__(16) unsigned short Bs[BN * BK];

  const int z = blockIdx.z;
  const unsigned short* A;
  const unsigned short* Bt;
  const float* bias;
  int mode;
  if (phase == 0) {
    A    = (z == 0) ? xb : yb;
    Bt   = WtAll + (size_t)z * EMB * EMB;
    bias = (z == 0) ? bq : (z == 1) ? bk : bv;
    mode = z;                 // 0:Q 1:K 2:V(transposed out)
  } else {
    A = attnb; Bt = WtAll + (size_t)3 * EMB * EMB; bias = bo; mode = 3;
  }

  const int tid = threadIdx.x;
  const int lane = tid & 63, wid = tid >> 6;
  const int wr = wid >> 1, wc = wid & 1;
  const int l15 = lane & 15, l4 = lane >> 4;
  const int m0 = blockIdx.y * BM, n0 = blockIdx.x * BN;

  const int crow = tid >> 2;   // 0..63 (+64 for it=1)
  const int cslot = tid & 3;

  f32x4 acc[4][4] = {};

  for (int kt = 0; kt < EMB; kt += BK) {
#pragma unroll
    for (int it = 0; it < 2; ++it)
      async_load16(A + (size_t)(m0 + it * 64 + crow) * EMB + kt + cslot * 8,
                   (char*)As + it * 4096 + wid * 1024);
#pragma unroll
    for (int it = 0; it < 2; ++it)
      async_load16(Bt + (size_t)(n0 + it * 64 + crow) * EMB + kt + cslot * 8,
                   (char*)Bs + it * 4096 + wid * 1024);
    __syncthreads();

    bf16x8 af[4], bfr[4];
#pragma unroll
    for (int i = 0; i < 4; ++i) {
      af[i]  = *reinterpret_cast<const bf16x8*>((const char*)As + (wr * 64 + i * 16 + l15) * 64 + l4 * 16);
      bfr[i] = *reinterpret_cast<const bf16x8*>((const char*)Bs + (wc * 64 + i * 16 + l15) * 64 + l4 * 16);
    }
#pragma unroll
    for (int i = 0; i < 4; ++i)
#pragma unroll
      for (int j = 0; j < 4; ++j)
        acc[i][j] = __builtin_amdgcn_mfma_f32_16x16x32_bf16(af[i], bfr[j], acc[i][j], 0, 0, 0);
    __syncthreads();
  }

  // epilogue: C/D layout col=lane&15, row=(lane>>4)*4+reg (m89/m91 verified)
#pragma unroll
  for (int i = 0; i < 4; ++i) {
#pragma unroll
    for (int j = 0; j < 4; ++j) {
      const int col = n0 + wc * 64 + j * 16 + l15;
      const float bsv = bias[col];
#pragma unroll
      for (int r = 0; r < 4; ++r) {
        const int row = m0 + wr * 64 + i * 16 + l4 * 4 + r;
        const float v = acc[i][j][r] + bsv;
        if (mode == 3) {
          dout[(size_t)row * EMB + col] = v;
        } else {
          const int b = row >> 11, n = row & (SEQ - 1);
          const int h = col >> 6, d = col & (HD - 1);
          if (mode == 0)
            Qb[(((size_t)(b * NH + h)) * SEQ + n) * HD + d] = f2bf(v);
          else if (mode == 1)
            Kb[(((size_t)(b * NH + h)) * SEQ + n) * HD + d] = f2bf(v);
          else
            Vt[(((size_t)(b * NH + h)) * HD + d) * SEQ + n] = f2bf(v);
        }
      }
    }
  }
}

// ---------------- flash attention ----------------
// 4 waves x 32 q-rows, KBLK=64; K/V staged swizzled (both-sides XOR), P via LDS.
#define QBLK 128
#define KBLK 64

__global__ __launch_bounds__(256, 2) void flash_kernel(
    const unsigned short* __restrict__ Qb,
    const unsigned short* __restrict__ Kb,
    const unsigned short* __restrict__ Vt,
    unsigned short* __restrict__ attnb) {
  __shared__ __align__(16) char Ks[8192];   // [key][d] 64x64 bf16, XOR-swizzled
  __shared__ __align__(16) char Vs[8192];   // [d][key] 64x64 bf16, XOR-swizzled
  __shared__ __align__(16) char Ps[16384];  // per-wave [32][64] bf16, XOR-swizzled

  const int tid = threadIdx.x;
  const int lane = tid & 63, wid = tid >> 6;
  const int l15 = lane & 15, l4 = lane >> 4;
  const int bh = blockIdx.y;
  const int bb = bh >> 4, hh = bh & 15;
  const int q0 = blockIdx.x * QBLK + wid * 32;

  const unsigned short* Qp = Qb + (size_t)bh * SEQ * HD;
  const unsigned short* Kp = Kb + (size_t)bh * SEQ * HD;
  const unsigned short* Vp = Vt + (size_t)bh * HD * SEQ;

  // Q fragments in registers (A-operand: row=l&15, k=(l>>4)*8+j)
  bf16x8 qf[2][2];
#pragma unroll
  for (int mi = 0; mi < 2; ++mi)
#pragma unroll
    for (int kk = 0; kk < 2; ++kk)
      qf[mi][kk] = *reinterpret_cast<const bf16x8*>(
          Qp + (size_t)(q0 + mi * 16 + l15) * HD + kk * 32 + l4 * 8);

  f32x4 accO[2][4] = {};
  float mI[2][4], lI[2][4];
#pragma unroll
  for (int mi = 0; mi < 2; ++mi)
#pragma unroll
    for (int r = 0; r < 4; ++r) { mI[mi][r] = -1e30f; lI[mi][r] = 0.f; }

  char* Pw = Ps + wid * 4096;

  for (int kt = 0; kt < SEQ; kt += KBLK) {
    // stage K tile: LDS linear = row*128 + s*16 holds K[row][(s^(row&7))*8 ..+8]
#pragma unroll
    for (int it = 0; it < 2; ++it) {
      const int row = it * 32 + (tid >> 3);
      const int s = tid & 7;
      async_load16(Kp + (size_t)(kt + row) * HD + ((s ^ (row & 7)) * 8),
                   Ks + it * 4096 + wid * 1024);
    }
#pragma unroll
    for (int it = 0; it < 2; ++it) {
      const int d = it * 32 + (tid >> 3);
      const int s = tid & 7;
      async_load16(Vp + (size_t)d * SEQ + kt + ((s ^ (d & 7)) * 8),
                   Vs + it * 4096 + wid * 1024);
    }
    __syncthreads();

    // S = Q K^T   (B-operand: col=key=l&15, k=d=(l>>4)*8+j)
    bf16x8 kf[4][2];
#pragma unroll
    for (int nk = 0; nk < 4; ++nk)
#pragma unroll
      for (int kk = 0; kk < 2; ++kk) {
        const int key = nk * 16 + l15;
        kf[nk][kk] = *reinterpret_cast<const bf16x8*>(
            Ks + key * 128 + (((kk * 4 + l4) ^ (key & 7)) * 16));
      }
    f32x4 sc[2][4] = {};
#pragma unroll
    for (int mi = 0; mi < 2; ++mi)
#pragma unroll
      for (int nk = 0; nk < 4; ++nk)
#pragma unroll
        for (int kk = 0; kk < 2; ++kk)
          sc[mi][nk] = __builtin_amdgcn_mfma_f32_16x16x32_bf16(qf[mi][kk], kf[nk][kk], sc[mi][nk], 0, 0, 0);

    // online softmax: row = mi*16 + l4*4 + r, cols spread over l15 x nk
#pragma unroll
    for (int mi = 0; mi < 2; ++mi) {
#pragma unroll
      for (int r = 0; r < 4; ++r) {
        float pm = fmaxf(fmaxf(sc[mi][0][r], sc[mi][1][r]), fmaxf(sc[mi][2][r], sc[mi][3][r]));
        pm = fmaxf(pm, __shfl_xor(pm, 1));
        pm = fmaxf(pm, __shfl_xor(pm, 2));
        pm = fmaxf(pm, __shfl_xor(pm, 4));
        pm = fmaxf(pm, __shfl_xor(pm, 8));
        const float mnew = fmaxf(mI[mi][r], pm);
        const float scl = __expf(mI[mi][r] - mnew);
        mI[mi][r] = mnew;
        lI[mi][r] *= scl;
#pragma unroll
        for (int ni = 0; ni < 4; ++ni) accO[mi][ni][r] *= scl;
        float ps = 0.f;
        const int rowL = mi * 16 + l4 * 4 + r;
#pragma unroll
        for (int nk = 0; nk < 4; ++nk) {
          const float p = __expf(sc[mi][nk][r] - mnew);
          ps += p;
          const int key = nk * 16 + l15;
          *reinterpret_cast<unsigned short*>(
              Pw + rowL * 128 + (((key >> 3) ^ (rowL & 7)) * 16) + (key & 7) * 2) = f2bf(p);
        }
        ps += __shfl_xor(ps, 1);
        ps += __shfl_xor(ps, 2);
        ps += __shfl_xor(ps, 4);
        ps += __shfl_xor(ps, 8);
        lI[mi][r] += ps;
      }
    }
    __syncthreads();   // P visible (cross-lane transpose through LDS)

    // O += P V  (A=P: row=q=l&15, k=key; B=V: col=d=l&15, k=key)
    bf16x8 vf[4][2];
#pragma unroll
    for (int ni = 0; ni < 4; ++ni)
#pragma unroll
      for (int kk = 0; kk < 2; ++kk) {
        const int d = ni * 16 + l15;
        vf[ni][kk] = *reinterpret_cast<const bf16x8*>(
            Vs + d * 128 + (((kk * 4 + l4) ^ (d & 7)) * 16));
      }
    bf16x8 pf[2][2];
#pragma unroll
    for (int mi = 0; mi < 2; ++mi)
#pragma unroll
      for (int kk = 0; kk < 2; ++kk) {
        const int rowL = mi * 16 + l15;
        pf[mi][kk] = *reinterpret_cast<const bf16x8*>(
            Pw + rowL * 128 + (((kk * 4 + l4) ^ (rowL & 7)) * 16));
      }
#pragma unroll
    for (int mi = 0; mi < 2; ++mi)
#pragma unroll
      for (int ni = 0; ni < 4; ++ni)
#pragma unroll
        for (int kk = 0; kk < 2; ++kk)
          accO[mi][ni] = __builtin_amdgcn_mfma_f32_16x16x32_bf16(pf[mi][kk], vf[ni][kk], accO[mi][ni], 0, 0, 0);
    __syncthreads();   // protect Ks/Vs/Ps before next stage
  }

  // epilogue: O = acc / (l * sqrt(E)), sqrt(1024)=32
#pragma unroll
  for (int mi = 0; mi < 2; ++mi)
#pragma unroll
    for (int ni = 0; ni < 4; ++ni)
#pragma unroll
      for (int r = 0; r < 4; ++r) {
        const int q = q0 + mi * 16 + l4 * 4 + r;
        const int col = hh * HD + ni * 16 + l15;
        const float ov = accO[mi][ni][r] / (lI[mi][r] * 32.0f);
        attnb[((size_t)(bb * SEQ + q)) * EMB + col] = f2bf(ov);
      }
}

extern "C" void kernel_launch(void* const* d_in, const int* in_sizes, int n_in,
                              void* d_out, int out_size, void* d_ws, size_t ws_size,
                              hipStream_t stream) {
  (void)in_sizes; (void)n_in; (void)out_size;
  const float* x  = (const float*)d_in[0];
  const float* y  = (const float*)d_in[1];
  const float* Wq = (const float*)d_in[2];
  const float* bq = (const float*)d_in[3];
  const float* Wk = (const float*)d_in[4];
  const float* bk = (const float*)d_in[5];
  const float* Wv = (const float*)d_in[6];
  const float* bv = (const float*)d_in[7];
  const float* Wo = (const float*)d_in[8];
  const float* bo = (const float*)d_in[9];
  float* out = (float*)d_out;

  char* ws = (char*)d_ws;
  unsigned short* xb    = (unsigned short*)(ws + (size_t)(0u  << 20));
  unsigned short* yb    = (unsigned short*)(ws + (size_t)(8u  << 20));
  unsigned short* WtAll = (unsigned short*)(ws + (size_t)(16u << 20));
  unsigned short* Qb    = (unsigned short*)(ws + (size_t)(24u << 20));
  unsigned short* Kb    = (unsigned short*)(ws + (size_t)(32u << 20));
  unsigned short* Vt    = (unsigned short*)(ws + (size_t)(40u << 20));
  unsigned short* attnb = (unsigned short*)(ws + (size_t)(48u << 20));
  if (ws_size < ((size_t)56u << 20)) return;  // need 56 MB scratch

  const int n4 = (BATCH * SEQ * EMB) / 4;  // 1048576
  hipLaunchKernelGGL(convert_kernel, dim3(n4 / 256), dim3(256), 0, stream, x, xb, n4);
  hipLaunchKernelGGL(convert_kernel, dim3(n4 / 256), dim3(256), 0, stream, y, yb, n4);
  hipLaunchKernelGGL(transw_kernel, dim3(16, 16, 4), dim3(256), 0, stream, Wq, Wk, Wv, Wo, WtAll);
  hipLaunchKernelGGL(gemm_kernel, dim3(EMB / BN, MROWS / BM, 3), dim3(256), 0, stream,
                     xb, yb, attnb, WtAll, bq, bk, bv, bo, Qb, Kb, Vt, out, 0);
  hipLaunchKernelGGL(flash_kernel, dim3(SEQ / QBLK, BATCH * NH), dim3(256), 0, stream,
                     Qb, Kb, Vt, attnb);
  hipLaunchKernelGGL(gemm_kernel, dim3(EMB / BN, MROWS / BM, 1), dim3(256), 0, stream,
                     xb, yb, attnb, WtAll, bq, bk, bv, bo, Qb, Kb, Vt, out, 1);
}

// Round 2
// 207.527 us; speedup vs baseline: 1.0084x; 1.0084x over previous
//
#include <hip/hip_runtime.h>
#include <stdint.h>

#define BATCH 2
#define SEQ   2048
#define EMB   1024
#define NH    16
#define HD    64
#define MROWS (BATCH*SEQ)   // 4096

using bf16x8 = __attribute__((ext_vector_type(8))) short;
using f32x4  = __attribute__((ext_vector_type(4))) float;
using f32x16 = __attribute__((ext_vector_type(16))) float;

__device__ __forceinline__ unsigned short f2bf(float f) {
  __bf16 b = (__bf16)f;                       // RNE fptrunc
  return __builtin_bit_cast(unsigned short, b);
}

__device__ __forceinline__ unsigned int cvtpk_bf16(float lo, float hi) {
  unsigned int w;
  asm("v_cvt_pk_bf16_f32 %0, %1, %2" : "=v"(w) : "v"(lo), "v"(hi));
  return w;
}

__device__ __forceinline__ void async_load16(const void* g, void* l) {
  __builtin_amdgcn_global_load_lds(
      (__attribute__((address_space(1))) void*)g,
      (__attribute__((address_space(3))) void*)l,
      16, 0, 0);
}

// ---------------- f32 -> bf16 bulk convert ----------------
__global__ __launch_bounds__(256) void convert_kernel(
    const float* __restrict__ in, unsigned short* __restrict__ out, int n4) {
  int i = blockIdx.x * blockDim.x + threadIdx.x;
  if (i >= n4) return;
  const float4 v = reinterpret_cast<const float4*>(in)[i];
  ushort4 o;
  o.x = f2bf(v.x); o.y = f2bf(v.y); o.z = f2bf(v.z); o.w = f2bf(v.w);
  reinterpret_cast<ushort4*>(out)[i] = o;
}

// ---------------- weight transpose + convert: Wt[n][k] = W[k][n] ----------------
__global__ __launch_bounds__(256) void transw_kernel(
    const float* __restrict__ Wq, const float* __restrict__ Wk,
    const float* __restrict__ Wv, const float* __restrict__ Wo,
    unsigned short* __restrict__ WtAll) {
  const int z = blockIdx.z;
  const float* W = (z == 0) ? Wq : (z == 1) ? Wk : (z == 2) ? Wv : Wo;
  unsigned short* Wt = WtAll + (size_t)z * EMB * EMB;
  __shared__ unsigned short tile[64][65];
  const int tc = threadIdx.x & 15;
  const int tr = threadIdx.x >> 4;
  const int n0 = blockIdx.x * 64, k0 = blockIdx.y * 64;
#pragma unroll
  for (int rr = 0; rr < 4; ++rr) {
    const int row = rr * 16 + tr;  // k-local
    float4 v = *reinterpret_cast<const float4*>(W + (size_t)(k0 + row) * EMB + n0 + tc * 4);
    tile[tc * 4 + 0][row] = f2bf(v.x);
    tile[tc * 4 + 1][row] = f2bf(v.y);
    tile[tc * 4 + 2][row] = f2bf(v.z);
    tile[tc * 4 + 3][row] = f2bf(v.w);
  }
  __syncthreads();
#pragma unroll
  for (int rr = 0; rr < 4; ++rr) {
    const int row = rr * 16 + tr;  // n-local
    ushort4 o;
    o.x = tile[row][tc * 4 + 0];
    o.y = tile[row][tc * 4 + 1];
    o.z = tile[row][tc * 4 + 2];
    o.w = tile[row][tc * 4 + 3];
    *reinterpret_cast<ushort4*>(Wt + (size_t)(n0 + row) * EMB + k0 + tc * 4) = o;
  }
}

// ---------------- GEMM: C[m][n] = A[m][:] . Wt[n][:] + bias[n] ----------------
#define BM 128
#define BN 128
#define BK 32

__global__ __launch_bounds__(256, 2) void gemm_kernel(
    const unsigned short* __restrict__ xb,
    const unsigned short* __restrict__ yb,
    const unsigned short* __restrict__ attnb,
    const unsigned short* __restrict__ WtAll,
    const float* __restrict__ bq, const float* __restrict__ bk,
    const float* __restrict__ bv, const float* __restrict__ bo,
    unsigned short* __restrict__ Qb, unsigned short* __restrict__ Kb,
    unsigned short* __restrict__ Vt, float* __restrict__ dout,
    int phase) {
  __shared__ __align__(16) unsigned short As[BM * BK];
  __shared__ __align__(16) unsigned short Bs[BN * BK];

  const int z = blockIdx.z;
  const unsigned short* A;
  const unsigned short* Bt;
  const float* bias;
  int mode;
  if (phase == 0) {
    A    = (z == 0) ? xb : yb;
    Bt   = WtAll + (size_t)z * EMB * EMB;
    bias = (z == 0) ? bq : (z == 1) ? bk : bv;
    mode = z;                 // 0:Q 1:K 2:V(transposed out)
  } else {
    A = attnb; Bt = WtAll + (size_t)3 * EMB * EMB; bias = bo; mode = 3;
  }

  const int tid = threadIdx.x;
  const int lane = tid & 63, wid = tid >> 6;
  const int wr = wid >> 1, wc = wid & 1;
  const int l15 = lane & 15, l4 = lane >> 4;
  const int m0 = blockIdx.y * BM, n0 = blockIdx.x * BN;

  const int crow = tid >> 2;   // 0..63 (+64 for it=1)
  const int cslot = tid & 3;

  f32x4 acc[4][4] = {};

  for (int kt = 0; kt < EMB; kt += BK) {
#pragma unroll
    for (int it = 0; it < 2; ++it)
      async_load16(A + (size_t)(m0 + it * 64 + crow) * EMB + kt + cslot * 8,
                   (char*)As + it * 4096 + wid * 1024);
#pragma unroll
    for (int it = 0; it < 2; ++it)
      async_load16(Bt + (size_t)(n0 + it * 64 + crow) * EMB + kt + cslot * 8,
                   (char*)Bs + it * 4096 + wid * 1024);
    __syncthreads();

    bf16x8 af[4], bfr[4];
#pragma unroll
    for (int i = 0; i < 4; ++i) {
      af[i]  = *reinterpret_cast<const bf16x8*>((const char*)As + (wr * 64 + i * 16 + l15) * 64 + l4 * 16);
      bfr[i] = *reinterpret_cast<const bf16x8*>((const char*)Bs + (wc * 64 + i * 16 + l15) * 64 + l4 * 16);
    }
#pragma unroll
    for (int i = 0; i < 4; ++i)
#pragma unroll
      for (int j = 0; j < 4; ++j)
        acc[i][j] = __builtin_amdgcn_mfma_f32_16x16x32_bf16(af[i], bfr[j], acc[i][j], 0, 0, 0);
    __syncthreads();
  }

  // epilogue: C/D layout col=lane&15, row=(lane>>4)*4+reg (m89/m91 verified)
#pragma unroll
  for (int i = 0; i < 4; ++i) {
#pragma unroll
    for (int j = 0; j < 4; ++j) {
      const int col = n0 + wc * 64 + j * 16 + l15;
      const float bsv = bias[col];
#pragma unroll
      for (int r = 0; r < 4; ++r) {
        const int row = m0 + wr * 64 + i * 16 + l4 * 4 + r;
        const float v = acc[i][j][r] + bsv;
        if (mode == 3) {
          dout[(size_t)row * EMB + col] = v;
        } else {
          const int b = row >> 11, n = row & (SEQ - 1);
          const int h = col >> 6, d = col & (HD - 1);
          if (mode == 0)
            Qb[(((size_t)(b * NH + h)) * SEQ + n) * HD + d] = f2bf(v);
          else if (mode == 1)
            Kb[(((size_t)(b * NH + h)) * SEQ + n) * HD + d] = f2bf(v);
          else
            Vt[(((size_t)(b * NH + h)) * HD + d) * SEQ + n] = f2bf(v);
        }
      }
    }
  }
}

// ---------------- flash attention (LDS-free, swapped QK^T, 32x32x16 MFMA) ----
// Each wave owns 32 q-rows. S^T = mfma(A=K, B=Q): C col=q=lane&31,
// row=key=(reg&3)+8*(reg>>2)+4*(lane>>5) -> softmax state (m,l) is per-lane.
// PV: O^T = mfma(A=V^T (from Vt), B=P^T). P packed in-register via
// v_cvt_pk_bf16_f32 + one shfl_xor(32) exchange per word pair.
#define KVB 64

__global__ __launch_bounds__(256, 2) void flash_kernel(
    const unsigned short* __restrict__ Qb,
    const unsigned short* __restrict__ Kb,
    const unsigned short* __restrict__ Vt,
    unsigned short* __restrict__ attnb) {
  const int tid = threadIdx.x;
  const int lane = tid & 63, wid = tid >> 6;
  const int l31 = lane & 31, hi = lane >> 5;
  const int bh = blockIdx.y;
  const int bb = bh >> 4, hh = bh & 15;
  const int q0 = blockIdx.x * 128 + wid * 32;

  const unsigned short* Qp = Qb + (size_t)bh * SEQ * HD;
  const unsigned short* Kp = Kb + (size_t)bh * SEQ * HD;
  const unsigned short* Vp = Vt + (size_t)bh * HD * SEQ;

  // Q B-frags: col=q=l31, k=d = kt*16 + hi*8 + j
  bf16x8 qf[4];
#pragma unroll
  for (int kt = 0; kt < 4; ++kt)
    qf[kt] = *reinterpret_cast<const bf16x8*>(Qp + (size_t)(q0 + l31) * HD + kt * 16 + hi * 8);

  f32x16 accO[2] = {};
  float mI = -1e30f, lI = 0.f;

  for (int kv = 0; kv < SEQ; kv += KVB) {
    // K A-frags: row=key = t*32+l31, k=d = kt*16+hi*8+j
    bf16x8 kf[2][4];
#pragma unroll
    for (int t = 0; t < 2; ++t)
#pragma unroll
      for (int kt = 0; kt < 4; ++kt)
        kf[t][kt] = *reinterpret_cast<const bf16x8*>(
            Kp + (size_t)(kv + t * 32 + l31) * HD + kt * 16 + hi * 8);
    // V A-frags: row=d = dt*32+l31, k=key = kt*16+hi*8+j
    bf16x8 vf[2][4];
#pragma unroll
    for (int dt = 0; dt < 2; ++dt)
#pragma unroll
      for (int kt = 0; kt < 4; ++kt)
        vf[dt][kt] = *reinterpret_cast<const bf16x8*>(
            Vp + (size_t)(dt * 32 + l31) * SEQ + kv + kt * 16 + hi * 8);

    // S^T = K . Q^T  (two 32-key tiles)
    f32x16 sc[2] = {};
#pragma unroll
    for (int t = 0; t < 2; ++t)
#pragma unroll
      for (int kt = 0; kt < 4; ++kt)
        sc[t] = __builtin_amdgcn_mfma_f32_32x32x16_bf16(kf[t][kt], qf[kt], sc[t], 0, 0, 0);

    // online softmax — per-lane scalar state (q = l31; keys split across hi pair)
    float mown = sc[0][0];
#pragma unroll
    for (int t = 0; t < 2; ++t)
#pragma unroll
      for (int r = 0; r < 16; ++r) mown = fmaxf(mown, sc[t][r]);
    mown = fmaxf(mown, __shfl_xor(mown, 32));
    const float mnew = fmaxf(mI, mown);
    const float scl = __expf(mI - mnew);
    mI = mnew;

    float p[2][16];
    float ls = 0.f;
#pragma unroll
    for (int t = 0; t < 2; ++t)
#pragma unroll
      for (int r = 0; r < 16; ++r) {
        p[t][r] = __expf(sc[t][r] - mnew);
        ls += p[t][r];
      }
    ls += __shfl_xor(ls, 32);
    lI = lI * scl + ls;
#pragma unroll
    for (int dt = 0; dt < 2; ++dt)
#pragma unroll
      for (int r = 0; r < 16; ++r) accO[dt][r] *= scl;

    // pack P into B-frags: frag kt covers keys kt*16..+15; lane needs k=hi*8+j
    bf16x8 pf[4];
#pragma unroll
    for (int kt = 0; kt < 4; ++kt) {
      const int t = kt >> 1, g = (kt & 1) * 8;
      // own regs g+c: key_local16 = (c&3) + 8*(c>>2) + 4*hi
      const unsigned int Aw = cvtpk_bf16(p[t][g + 0], p[t][g + 1]);  // keys 4hi+0,1
      const unsigned int Cw = cvtpk_bf16(p[t][g + 2], p[t][g + 3]);  // keys 4hi+2,3
      const unsigned int Bw = cvtpk_bf16(p[t][g + 4], p[t][g + 5]);  // keys 8+4hi+0,1
      const unsigned int Dw = cvtpk_bf16(p[t][g + 6], p[t][g + 7]);  // keys 8+4hi+2,3
      const unsigned int s1 = hi ? Aw : Bw;
      const unsigned int r1 = __shfl_xor(s1, 32);
      const unsigned int s2 = hi ? Cw : Dw;
      const unsigned int r2 = __shfl_xor(s2, 32);
      unsigned int w[4];
      w[0] = hi ? r1 : Aw;   // keys +0,+1
      w[1] = hi ? r2 : Cw;   // keys +2,+3
      w[2] = hi ? Bw : r1;   // keys +4,+5
      w[3] = hi ? Dw : r2;   // keys +6,+7
      union { unsigned int u[4]; bf16x8 v; } cvt;
      cvt.u[0] = w[0]; cvt.u[1] = w[1]; cvt.u[2] = w[2]; cvt.u[3] = w[3];
      pf[kt] = cvt.v;
    }

    // O^T += V^T . P  (two 32-d tiles)
#pragma unroll
    for (int dt = 0; dt < 2; ++dt)
#pragma unroll
      for (int kt = 0; kt < 4; ++kt)
        accO[dt] = __builtin_amdgcn_mfma_f32_32x32x16_bf16(vf[dt][kt], pf[kt], accO[dt], 0, 0, 0);
  }

  // epilogue: O = accO / (l * sqrt(E)); C row=d_local=(reg&3)+8*(reg>>2)+4*hi, col=q=l31
  const float inv = 1.0f / (lI * 32.0f);
  const size_t obase = ((size_t)(bb * SEQ + q0 + l31)) * EMB + hh * HD;
#pragma unroll
  for (int dt = 0; dt < 2; ++dt)
#pragma unroll
    for (int rr = 0; rr < 4; ++rr) {
      ushort4 o;
      o.x = f2bf(accO[dt][rr * 4 + 0] * inv);
      o.y = f2bf(accO[dt][rr * 4 + 1] * inv);
      o.z = f2bf(accO[dt][rr * 4 + 2] * inv);
      o.w = f2bf(accO[dt][rr * 4 + 3] * inv);
      *reinterpret_cast<ushort4*>(attnb + obase + dt * 32 + 8 * rr + 4 * hi) = o;
    }
}

extern "C" void kernel_launch(void* const* d_in, const int* in_sizes, int n_in,
                              void* d_out, int out_size, void* d_ws, size_t ws_size,
                              hipStream_t stream) {
  (void)in_sizes; (void)n_in; (void)out_size;
  const float* x  = (const float*)d_in[0];
  const float* y  = (const float*)d_in[1];
  const float* Wq = (const float*)d_in[2];
  const float* bq = (const float*)d_in[3];
  const float* Wk = (const float*)d_in[4];
  const float* bk = (const float*)d_in[5];
  const float* Wv = (const float*)d_in[6];
  const float* bv = (const float*)d_in[7];
  const float* Wo = (const float*)d_in[8];
  const float* bo = (const float*)d_in[9];
  float* out = (float*)d_out;

  char* ws = (char*)d_ws;
  unsigned short* xb    = (unsigned short*)(ws + (size_t)(0u  << 20));
  unsigned short* yb    = (unsigned short*)(ws + (size_t)(8u  << 20));
  unsigned short* WtAll = (unsigned short*)(ws + (size_t)(16u << 20));
  unsigned short* Qb    = (unsigned short*)(ws + (size_t)(24u << 20));
  unsigned short* Kb    = (unsigned short*)(ws + (size_t)(32u << 20));
  unsigned short* Vt    = (unsigned short*)(ws + (size_t)(40u << 20));
  unsigned short* attnb = (unsigned short*)(ws + (size_t)(48u << 20));
  if (ws_size < ((size_t)56u << 20)) return;  // need 56 MB scratch

  const int n4 = (BATCH * SEQ * EMB) / 4;  // 1048576
  hipLaunchKernelGGL(convert_kernel, dim3(n4 / 256), dim3(256), 0, stream, x, xb, n4);
  hipLaunchKernelGGL(convert_kernel, dim3(n4 / 256), dim3(256), 0, stream, y, yb, n4);
  hipLaunchKernelGGL(transw_kernel, dim3(16, 16, 4), dim3(256), 0, stream, Wq, Wk, Wv, Wo, WtAll);
  hipLaunchKernelGGL(gemm_kernel, dim3(EMB / BN, MROWS / BM, 3), dim3(256), 0, stream,
                     xb, yb, attnb, WtAll, bq, bk, bv, bo, Qb, Kb, Vt, out, 0);
  hipLaunchKernelGGL(flash_kernel, dim3(SEQ / 128, BATCH * NH), dim3(256), 0, stream,
                     Qb, Kb, Vt, attnb);
  hipLaunchKernelGGL(gemm_kernel, dim3(EMB / BN, MROWS / BM, 1), dim3(256), 0, stream,
                     xb, yb, attnb, WtAll, bq, bk, bv, bo, Qb, Kb, Vt, out, 1);
}

// Round 3
// 157.919 us; speedup vs baseline: 1.3251x; 1.3141x over previous
//
#include <hip/hip_runtime.h>
#include <stdint.h>

#define BATCH 2
#define SEQ   2048
#define EMB   1024
#define NH    16
#define HD    64
#define MROWS (BATCH*SEQ)   // 4096

using bf16x8 = __attribute__((ext_vector_type(8))) short;
using f32x4  = __attribute__((ext_vector_type(4))) float;
using f32x16 = __attribute__((ext_vector_type(16))) float;

__device__ __forceinline__ unsigned short f2bf(float f) {
  __bf16 b = (__bf16)f;                       // RNE fptrunc
  return __builtin_bit_cast(unsigned short, b);
}

__device__ __forceinline__ unsigned int cvtpk_bf16(float lo, float hi) {
  unsigned int w;
  asm("v_cvt_pk_bf16_f32 %0, %1, %2" : "=v"(w) : "v"(lo), "v"(hi));
  return w;
}

__device__ __forceinline__ void async_load16(const void* g, void* l) {
  __builtin_amdgcn_global_load_lds(
      (__attribute__((address_space(1))) void*)g,
      (__attribute__((address_space(3))) void*)l,
      16, 0, 0);
}

// ---------------- f32 -> bf16 bulk convert ----------------
__global__ __launch_bounds__(256) void convert_kernel(
    const float* __restrict__ in, unsigned short* __restrict__ out, int n4) {
  int i = blockIdx.x * blockDim.x + threadIdx.x;
  if (i >= n4) return;
  const float4 v = reinterpret_cast<const float4*>(in)[i];
  ushort4 o;
  o.x = f2bf(v.x); o.y = f2bf(v.y); o.z = f2bf(v.z); o.w = f2bf(v.w);
  reinterpret_cast<ushort4*>(out)[i] = o;
}

// ---------------- weight transpose + convert: Wt[n][k] = W[k][n] ----------------
__global__ __launch_bounds__(256) void transw_kernel(
    const float* __restrict__ Wq, const float* __restrict__ Wk,
    const float* __restrict__ Wv, const float* __restrict__ Wo,
    unsigned short* __restrict__ WtAll) {
  const int z = blockIdx.z;
  const float* W = (z == 0) ? Wq : (z == 1) ? Wk : (z == 2) ? Wv : Wo;
  unsigned short* Wt = WtAll + (size_t)z * EMB * EMB;
  __shared__ unsigned short tile[64][65];
  const int tc = threadIdx.x & 15;
  const int tr = threadIdx.x >> 4;
  const int n0 = blockIdx.x * 64, k0 = blockIdx.y * 64;
#pragma unroll
  for (int rr = 0; rr < 4; ++rr) {
    const int row = rr * 16 + tr;  // k-local
    float4 v = *reinterpret_cast<const float4*>(W + (size_t)(k0 + row) * EMB + n0 + tc * 4);
    tile[tc * 4 + 0][row] = f2bf(v.x);
    tile[tc * 4 + 1][row] = f2bf(v.y);
    tile[tc * 4 + 2][row] = f2bf(v.z);
    tile[tc * 4 + 3][row] = f2bf(v.w);
  }
  __syncthreads();
#pragma unroll
  for (int rr = 0; rr < 4; ++rr) {
    const int row = rr * 16 + tr;  // n-local
    ushort4 o;
    o.x = tile[row][tc * 4 + 0];
    o.y = tile[row][tc * 4 + 1];
    o.z = tile[row][tc * 4 + 2];
    o.w = tile[row][tc * 4 + 3];
    *reinterpret_cast<ushort4*>(Wt + (size_t)(n0 + row) * EMB + k0 + tc * 4) = o;
  }
}

// ---------------- GEMM: C[m][n] = A[m][:] . Wt[n][:] + bias[n] ----------------
#define BM 128
#define BN 128
#define BK 32

__global__ __launch_bounds__(256, 2) void gemm_kernel(
    const unsigned short* __restrict__ xb,
    const unsigned short* __restrict__ yb,
    const unsigned short* __restrict__ attnb,
    const unsigned short* __restrict__ WtAll,
    const float* __restrict__ bq, const float* __restrict__ bk,
    const float* __restrict__ bv, const float* __restrict__ bo,
    unsigned short* __restrict__ Qb, unsigned short* __restrict__ Kb,
    unsigned short* __restrict__ Vt, float* __restrict__ dout,
    int phase) {
  __shared__ __align__(16) unsigned short As[BM * BK];
  __shared__ __align__(16) unsigned short Bs[BN * BK];

  const int z = blockIdx.z;
  const unsigned short* A;
  const unsigned short* Bt;
  const float* bias;
  int mode;
  if (phase == 0) {
    A    = (z == 0) ? xb : yb;
    Bt   = WtAll + (size_t)z * EMB * EMB;
    bias = (z == 0) ? bq : (z == 1) ? bk : bv;
    mode = z;                 // 0:Q 1:K 2:V(transposed out)
  } else {
    A = attnb; Bt = WtAll + (size_t)3 * EMB * EMB; bias = bo; mode = 3;
  }

  const int tid = threadIdx.x;
  const int lane = tid & 63, wid = tid >> 6;
  const int wr = wid >> 1, wc = wid & 1;
  const int l15 = lane & 15, l4 = lane >> 4;
  const int m0 = blockIdx.y * BM, n0 = blockIdx.x * BN;

  const int crow = tid >> 2;   // 0..63 (+64 for it=1)
  const int cslot = tid & 3;

  f32x4 acc[4][4] = {};

  for (int kt = 0; kt < EMB; kt += BK) {
#pragma unroll
    for (int it = 0; it < 2; ++it)
      async_load16(A + (size_t)(m0 + it * 64 + crow) * EMB + kt + cslot * 8,
                   (char*)As + it * 4096 + wid * 1024);
#pragma unroll
    for (int it = 0; it < 2; ++it)
      async_load16(Bt + (size_t)(n0 + it * 64 + crow) * EMB + kt + cslot * 8,
                   (char*)Bs + it * 4096 + wid * 1024);
    __syncthreads();

    bf16x8 af[4], bfr[4];
#pragma unroll
    for (int i = 0; i < 4; ++i) {
      af[i]  = *reinterpret_cast<const bf16x8*>((const char*)As + (wr * 64 + i * 16 + l15) * 64 + l4 * 16);
      bfr[i] = *reinterpret_cast<const bf16x8*>((const char*)Bs + (wc * 64 + i * 16 + l15) * 64 + l4 * 16);
    }
#pragma unroll
    for (int i = 0; i < 4; ++i)
#pragma unroll
      for (int j = 0; j < 4; ++j)
        acc[i][j] = __builtin_amdgcn_mfma_f32_16x16x32_bf16(af[i], bfr[j], acc[i][j], 0, 0, 0);
    __syncthreads();
  }

  // epilogue: C/D layout col=lane&15, row=(lane>>4)*4+reg (m89/m91 verified)
#pragma unroll
  for (int i = 0; i < 4; ++i) {
#pragma unroll
    for (int j = 0; j < 4; ++j) {
      const int col = n0 + wc * 64 + j * 16 + l15;
      const float bsv = bias[col];
#pragma unroll
      for (int r = 0; r < 4; ++r) {
        const int row = m0 + wr * 64 + i * 16 + l4 * 4 + r;
        const float v = acc[i][j][r] + bsv;
        if (mode == 3) {
          dout[(size_t)row * EMB + col] = v;
        } else {
          const int b = row >> 11, n = row & (SEQ - 1);
          const int h = col >> 6, d = col & (HD - 1);
          if (mode == 0)
            Qb[(((size_t)(b * NH + h)) * SEQ + n) * HD + d] = f2bf(v);
          else if (mode == 1)
            Kb[(((size_t)(b * NH + h)) * SEQ + n) * HD + d] = f2bf(v);
          else
            Vt[(((size_t)(b * NH + h)) * HD + d) * SEQ + n] = f2bf(v);
        }
      }
    }
  }
}

// ---------------- flash attention ----------------
// 2 waves x 32 q-rows, KVB=64. Swapped QK^T (S^T = mfma(K,Q), 32x32x16):
// softmax state is per-lane scalar. K/V staged coalesced via global_load_lds
// into double-buffered XOR-swizzled LDS (linear dest + inverse-swizzled
// source + swizzled ds_read — rule #21). 2-phase pipeline: stage(t+1) issued
// before compute(t); one barrier per iter. XCD swizzle: 4 heads per XCD so
// K/V stays L2-resident.
#define KVB 64
#define NT  (SEQ/KVB)   // 32

__global__ __launch_bounds__(128, 2) void flash_kernel(
    const unsigned short* __restrict__ Qb,
    const unsigned short* __restrict__ Kb,
    const unsigned short* __restrict__ Vt,
    unsigned short* __restrict__ attnb) {
  __shared__ __align__(16) char Ks[2][8192];   // [key][d] 64x64 bf16, swizzled
  __shared__ __align__(16) char Vs[2][8192];   // [d][key] 64x64 bf16, swizzled

  const int tid = threadIdx.x;                 // 0..127
  const int lane = tid & 63, wid = tid >> 6;   // 2 waves
  const int l31 = lane & 31, hi = lane >> 5;

  // XCD-aware decode: grid=1024 linear; XCD k (= lin%8) gets bh in [4k,4k+4)
  const int lin = blockIdx.x;
  const int swz = (lin & 7) * 128 + (lin >> 3);
  const int bh = swz >> 5;                     // 0..31
  const int qt = swz & 31;                     // 0..31
  const int bb = bh >> 4, hh = bh & 15;
  const int q0 = qt * 64 + wid * 32;

  const unsigned short* Qp = Qb + (size_t)bh * SEQ * HD;
  const unsigned short* Kp = Kb + (size_t)bh * SEQ * HD;
  const unsigned short* Vp = Vt + (size_t)bh * HD * SEQ;

  const int srow = tid >> 3;                   // 0..15 (staging row within it)
  const int sslot = tid & 7;

  // ---- prologue: stage tile 0, load Q frags ----
#pragma unroll
  for (int it = 0; it < 4; ++it) {
    const int r = it * 16 + srow;
    async_load16(Kp + (size_t)r * HD + ((sslot ^ (r & 7)) * 8),
                 Ks[0] + it * 2048 + wid * 1024);
    async_load16(Vp + (size_t)r * SEQ + 0 + ((sslot ^ (r & 7)) * 8),
                 Vs[0] + it * 2048 + wid * 1024);
  }

  // Q B-frags: col=q=l31, k=d = kt*16 + hi*8 + j
  bf16x8 qf[4];
#pragma unroll
  for (int kt = 0; kt < 4; ++kt)
    qf[kt] = *reinterpret_cast<const bf16x8*>(Qp + (size_t)(q0 + l31) * HD + kt * 16 + hi * 8);

  f32x16 accO[2] = {};
  float mI = -1e30f, lI = 0.f;

  __syncthreads();

  int buf = 0;
  for (int t = 0; t < NT; ++t) {
    // ---- issue stage(t+1) into buf^1 (flies under compute below) ----
    if (t + 1 < NT) {
      const int kvn = (t + 1) * KVB;
#pragma unroll
      for (int it = 0; it < 4; ++it) {
        const int r = it * 16 + srow;
        async_load16(Kp + (size_t)(kvn + r) * HD + ((sslot ^ (r & 7)) * 8),
                     Ks[buf ^ 1] + it * 2048 + wid * 1024);
        async_load16(Vp + (size_t)r * SEQ + kvn + ((sslot ^ (r & 7)) * 8),
                     Vs[buf ^ 1] + it * 2048 + wid * 1024);
      }
    }

    // ---- QK^T from Ks[buf]: kf row=key=t2*32+l31, k-chunk d0=kt*2+hi ----
    bf16x8 kf[2][4];
#pragma unroll
    for (int t2 = 0; t2 < 2; ++t2)
#pragma unroll
      for (int kt = 0; kt < 4; ++kt) {
        const int key = t2 * 32 + l31;
        kf[t2][kt] = *reinterpret_cast<const bf16x8*>(
            Ks[buf] + key * 128 + (((kt * 2 + hi) ^ (key & 7)) * 16));
      }
    f32x16 sc[2] = {};
#pragma unroll
    for (int t2 = 0; t2 < 2; ++t2)
#pragma unroll
      for (int kt = 0; kt < 4; ++kt)
        sc[t2] = __builtin_amdgcn_mfma_f32_32x32x16_bf16(kf[t2][kt], qf[kt], sc[t2], 0, 0, 0);

    // ---- online softmax (per-lane scalar state; q=l31, keys split over hi) ----
    float mown = sc[0][0];
#pragma unroll
    for (int t2 = 0; t2 < 2; ++t2)
#pragma unroll
      for (int r = 0; r < 16; ++r) mown = fmaxf(mown, sc[t2][r]);
    mown = fmaxf(mown, __shfl_xor(mown, 32));
    const float mnew = fmaxf(mI, mown);
    const float scl = __expf(mI - mnew);
    mI = mnew;

    float p[2][16];
    float ls = 0.f;
#pragma unroll
    for (int t2 = 0; t2 < 2; ++t2)
#pragma unroll
      for (int r = 0; r < 16; ++r) {
        p[t2][r] = __expf(sc[t2][r] - mnew);
        ls += p[t2][r];
      }
    ls += __shfl_xor(ls, 32);
    lI = lI * scl + ls;
#pragma unroll
    for (int dt = 0; dt < 2; ++dt)
#pragma unroll
      for (int r = 0; r < 16; ++r) accO[dt][r] *= scl;

    // ---- pack P into B-frags in-register (cvt_pk + shfl_xor 32) ----
    bf16x8 pf[4];
#pragma unroll
    for (int kt = 0; kt < 4; ++kt) {
      const int t2 = kt >> 1, g = (kt & 1) * 8;
      const unsigned int Aw = cvtpk_bf16(p[t2][g + 0], p[t2][g + 1]);  // keys 4hi+0,1
      const unsigned int Cw = cvtpk_bf16(p[t2][g + 2], p[t2][g + 3]);  // keys 4hi+2,3
      const unsigned int Bw = cvtpk_bf16(p[t2][g + 4], p[t2][g + 5]);  // keys 8+4hi+0,1
      const unsigned int Dw = cvtpk_bf16(p[t2][g + 6], p[t2][g + 7]);  // keys 8+4hi+2,3
      const unsigned int s1 = hi ? Aw : Bw;
      const unsigned int r1 = __shfl_xor(s1, 32);
      const unsigned int s2 = hi ? Cw : Dw;
      const unsigned int r2 = __shfl_xor(s2, 32);
      union { unsigned int u[4]; bf16x8 v; } cvt;
      cvt.u[0] = hi ? r1 : Aw;   // keys +0,+1
      cvt.u[1] = hi ? r2 : Cw;   // keys +2,+3
      cvt.u[2] = hi ? Bw : r1;   // keys +4,+5
      cvt.u[3] = hi ? Dw : r2;   // keys +6,+7
      pf[kt] = cvt.v;
    }

    // ---- PV from Vs[buf]: vf row=d=dt*32+l31, k-chunk k0=kt*2+hi ----
    bf16x8 vf[2][4];
#pragma unroll
    for (int dt = 0; dt < 2; ++dt)
#pragma unroll
      for (int kt = 0; kt < 4; ++kt) {
        const int d = dt * 32 + l31;
        vf[dt][kt] = *reinterpret_cast<const bf16x8*>(
            Vs[buf] + d * 128 + (((kt * 2 + hi) ^ (d & 7)) * 16));
      }
#pragma unroll
    for (int dt = 0; dt < 2; ++dt)
#pragma unroll
      for (int kt = 0; kt < 4; ++kt)
        accO[dt] = __builtin_amdgcn_mfma_f32_32x32x16_bf16(vf[dt][kt], pf[kt], accO[dt], 0, 0, 0);

    __syncthreads();   // drains stage(t+1) loads + protects buf reuse
    buf ^= 1;
  }

  // epilogue: O = accO / (l * sqrt(E)); C row=d_local=(reg&3)+8*(reg>>2)+4*hi, col=q=l31
  const float inv = 1.0f / (lI * 32.0f);
  const size_t obase = ((size_t)(bb * SEQ + q0 + l31)) * EMB + hh * HD;
#pragma unroll
  for (int dt = 0; dt < 2; ++dt)
#pragma unroll
    for (int rr = 0; rr < 4; ++rr) {
      ushort4 o;
      o.x = f2bf(accO[dt][rr * 4 + 0] * inv);
      o.y = f2bf(accO[dt][rr * 4 + 1] * inv);
      o.z = f2bf(accO[dt][rr * 4 + 2] * inv);
      o.w = f2bf(accO[dt][rr * 4 + 3] * inv);
      *reinterpret_cast<ushort4*>(attnb + obase + dt * 32 + 8 * rr + 4 * hi) = o;
    }
}

extern "C" void kernel_launch(void* const* d_in, const int* in_sizes, int n_in,
                              void* d_out, int out_size, void* d_ws, size_t ws_size,
                              hipStream_t stream) {
  (void)in_sizes; (void)n_in; (void)out_size;
  const float* x  = (const float*)d_in[0];
  const float* y  = (const float*)d_in[1];
  const float* Wq = (const float*)d_in[2];
  const float* bq = (const float*)d_in[3];
  const float* Wk = (const float*)d_in[4];
  const float* bk = (const float*)d_in[5];
  const float* Wv = (const float*)d_in[6];
  const float* bv = (const float*)d_in[7];
  const float* Wo = (const float*)d_in[8];
  const float* bo = (const float*)d_in[9];
  float* out = (float*)d_out;

  char* ws = (char*)d_ws;
  unsigned short* xb    = (unsigned short*)(ws + (size_t)(0u  << 20));
  unsigned short* yb    = (unsigned short*)(ws + (size_t)(8u  << 20));
  unsigned short* WtAll = (unsigned short*)(ws + (size_t)(16u << 20));
  unsigned short* Qb    = (unsigned short*)(ws + (size_t)(24u << 20));
  unsigned short* Kb    = (unsigned short*)(ws + (size_t)(32u << 20));
  unsigned short* Vt    = (unsigned short*)(ws + (size_t)(40u << 20));
  unsigned short* attnb = (unsigned short*)(ws + (size_t)(48u << 20));
  if (ws_size < ((size_t)56u << 20)) return;  // need 56 MB scratch

  const int n4 = (BATCH * SEQ * EMB) / 4;  // 1048576
  hipLaunchKernelGGL(convert_kernel, dim3(n4 / 256), dim3(256), 0, stream, x, xb, n4);
  hipLaunchKernelGGL(convert_kernel, dim3(n4 / 256), dim3(256), 0, stream, y, yb, n4);
  hipLaunchKernelGGL(transw_kernel, dim3(16, 16, 4), dim3(256), 0, stream, Wq, Wk, Wv, Wo, WtAll);
  hipLaunchKernelGGL(gemm_kernel, dim3(EMB / BN, MROWS / BM, 3), dim3(256), 0, stream,
                     xb, yb, attnb, WtAll, bq, bk, bv, bo, Qb, Kb, Vt, out, 0);
  hipLaunchKernelGGL(flash_kernel, dim3(SEQ / KVB * BATCH * NH), dim3(128), 0, stream,
                     Qb, Kb, Vt, attnb);
  hipLaunchKernelGGL(gemm_kernel, dim3(EMB / BN, MROWS / BM, 1), dim3(256), 0, stream,
                     xb, yb, attnb, WtAll, bq, bk, bv, bo, Qb, Kb, Vt, out, 1);
}